// Round 11
// baseline (155.607 us; speedup 1.0000x reference)
//
#include <hip/hip_runtime.h>
#include <cstddef>

typedef float f4 __attribute__((ext_vector_type(4)));
typedef __bf16 bf16x8 __attribute__((ext_vector_type(8)));
typedef __bf16 bf16x4 __attribute__((ext_vector_type(4)));
typedef float f32x16 __attribute__((ext_vector_type(16)));

constexpr int D_ = 128;     // d_model
constexpr int LAYERS = 4;
constexpr int BM = 64;      // tokens per block
constexpr int NT = 512;     // 8 waves: 4 nf (32-n frags) x 2 tw (32-token groups)
constexpr int ROWB = 256;   // Ab row stride bytes (cur only: 128 bf16)

// XOR swizzle (T2/G4) for 256B rows: rows 0-15 -> distinct 16B slots, r/r+16 pair = 2-way (free).
__device__ __forceinline__ int swz(int row, int woff) {
    return row * ROWB + (woff ^ ((row & 15) << 4));
}

// prep: W^T in MFMA A-fragment order (R5 version).
// wt2[((d*4 + nf)*16 + kc)*512 + lane*8 + j] = W^T[d][n = nf*32 + (lane&31)]
//                                                  [k = kc*16 + (lane>>5)*8 + j]
// Layer 0 folds concat([x,x]): top+bot summed into k in [128,256), zeros below.
__global__ void prep(const float* __restrict__ Wl, __bf16* __restrict__ wt2) {
    int idx = blockIdx.x * 256 + threadIdx.x;        // 4*4*16*512 = 131072
    int j = idx & 7, lane = (idx >> 3) & 63, kc = (idx >> 9) & 15,
        nf = (idx >> 13) & 3, d = idx >> 15;
    int n  = nf * 32 + (lane & 31);
    int ks = kc * 16 + (lane >> 5) * 8 + j;
    float v;
    if (d == 0)
        v = (ks < 128) ? 0.f
                       : (Wl[(size_t)(ks - 128) * D_ + n] + Wl[(size_t)ks * D_ + n]);
    else
        v = Wl[(size_t)d * 2 * D_ * D_ + (size_t)ks * D_ + n];
    wt2[idx] = (__bf16)v;
}

#define MFMA32(A, B, C) __builtin_amdgcn_mfma_f32_32x32x16_bf16((A), (B), (C), 0, 0, 0)

__global__ __launch_bounds__(NT, 6)   // 85-VGPR cap: the level proven spill-free (R8: 84)
void moe_fwd(const float* __restrict__ x, const float* __restrict__ Wr,
             const __bf16* __restrict__ wt2, const float* __restrict__ bl,
             const float* __restrict__ We, const float* __restrict__ be,
             float* __restrict__ out)
{
    __shared__ char Ab[BM * ROWB];     // 16 KB: [token][128 k] bf16 swizzled — cur only
    __shared__ float PR[4][BM];        // per-nf estimator partials
    __shared__ float CSM[BM][4];       // per-token 0/1 gate coefs

    const int t    = threadIdx.x;
    const int m0   = blockIdx.x * BM;
    const int lane = t & 63, w = t >> 6;
    const int nf   = w >> 1;            // 0..3: n in [nf*32, nf*32+32)
    const int tw   = w & 1;             // 0..1: 32-token group
    const int lo5  = lane & 31, hi = lane >> 5;
    const int hi16 = hi * 16;
    const int tok0 = tw * 32 + lo5;     // this wave's token (B/D column)
    const int grp  = t >> 4, il = t & 15;   // 16 lanes per token row

    // ---- gates in f64 (wrv held in regs; per-token math identical to R4-R8) ----
    {
        f4 wrv[8];
        #pragma unroll
        for (int j = 0; j < 8; ++j)
            wrv[j] = *(const f4*)(Wr + (il * 8 + j) * 4);
        #pragma unroll
        for (int i = 0; i < 2; ++i) {
            const int row = i * 32 + grp;
            const f4* gx = (const f4*)(x + (size_t)(m0 + row) * D_ + il * 8);
            f4 lo = gx[0], hp = gx[1];
            double a0 = 0, a1 = 0, a2 = 0, a3 = 0;
            #pragma unroll
            for (int j = 0; j < 4; ++j) {
                double xv = (double)lo[j];
                a0 += xv * (double)wrv[j][0]; a1 += xv * (double)wrv[j][1];
                a2 += xv * (double)wrv[j][2]; a3 += xv * (double)wrv[j][3];
            }
            #pragma unroll
            for (int j = 0; j < 4; ++j) {
                double xv = (double)hp[j];
                a0 += xv * (double)wrv[4 + j][0]; a1 += xv * (double)wrv[4 + j][1];
                a2 += xv * (double)wrv[4 + j][2]; a3 += xv * (double)wrv[4 + j][3];
            }
            #pragma unroll
            for (int s = 1; s < 16; s <<= 1) {   // 16-lane f64 tree reduce
                a0 += __shfl_xor(a0, s, 16);
                a1 += __shfl_xor(a1, s, 16);
                a2 += __shfl_xor(a2, s, 16);
                a3 += __shfl_xor(a3, s, 16);
            }
            if (il == 0) {
                f4 c;
                c[0] = a0 > 0.0 ? 1.f : 0.f; c[1] = a1 > 0.0 ? 1.f : 0.f;
                c[2] = a2 > 0.0 ? 1.f : 0.f; c[3] = a3 > 0.0 ? 1.f : 0.f;
                *(f4*)(&CSM[row][0]) = c;
            }
        }
    }

    // ---- x B-frags -> registers (per-wave; latency hides under reduce+barrier) ----
    // xb[fi][j] = bf16( x[tok0][fi*16 + hi*8 + j] )
    bf16x8 xb[8];
    #pragma unroll
    for (int fi = 0; fi < 8; ++fi) {
        const f4* gx = (const f4*)(x + (size_t)(m0 + tok0) * D_ + fi * 16 + hi * 8);
        f4 a = gx[0], b = gx[1];
        xb[fi][0] = (__bf16)a[0]; xb[fi][1] = (__bf16)a[1];
        xb[fi][2] = (__bf16)a[2]; xb[fi][3] = (__bf16)a[3];
        xb[fi][4] = (__bf16)b[0]; xb[fi][5] = (__bf16)b[1];
        xb[fi][6] = (__bf16)b[2]; xb[fi][7] = (__bf16)b[3];
    }

    float outc = 0.f;
    __syncthreads();     // CSM visible (xb is per-wave registers)

    #pragma unroll
    for (int d = 0; d < LAYERS; ++d) {
        f32x16 acc;
        #pragma unroll
        for (int j = 0; j < 16; ++j) acc[j] = 0.f;

        const __bf16* wb = wt2 + ((size_t)(d * 4 + nf) * 16) * 512 + lane * 8;

        if (d == 0) {
            // layer 0: K=128, pure-register B (no LDS in loop at all)
            #pragma unroll
            for (int f = 8; f < 16; ++f) {
                bf16x8 wf = *(const bf16x8*)(wb + (size_t)f * 512);
                acc = MFMA32(wf, xb[f - 8], acc);
            }
        } else {
            // issue first half of cur reads; x-half MFMAs cover the latency
            bf16x8 cb0 = *(const bf16x8*)(Ab + swz(tok0, 0 * 32 + hi16));
            bf16x8 cb1 = *(const bf16x8*)(Ab + swz(tok0, 1 * 32 + hi16));
            bf16x8 cb2 = *(const bf16x8*)(Ab + swz(tok0, 2 * 32 + hi16));
            bf16x8 cb3 = *(const bf16x8*)(Ab + swz(tok0, 3 * 32 + hi16));
            #pragma unroll
            for (int f = 8; f < 16; ++f) {
                bf16x8 wf = *(const bf16x8*)(wb + (size_t)f * 512);
                acc = MFMA32(wf, xb[f - 8], acc);
            }
            bf16x8 cb4 = *(const bf16x8*)(Ab + swz(tok0, 4 * 32 + hi16));
            bf16x8 cb5 = *(const bf16x8*)(Ab + swz(tok0, 5 * 32 + hi16));
            bf16x8 cb6 = *(const bf16x8*)(Ab + swz(tok0, 6 * 32 + hi16));
            bf16x8 cb7 = *(const bf16x8*)(Ab + swz(tok0, 7 * 32 + hi16));
            {
                bf16x8 wf;
                wf = *(const bf16x8*)(wb + 0 * 512); acc = MFMA32(wf, cb0, acc);
                wf = *(const bf16x8*)(wb + 1 * 512); acc = MFMA32(wf, cb1, acc);
                wf = *(const bf16x8*)(wb + 2 * 512); acc = MFMA32(wf, cb2, acc);
                wf = *(const bf16x8*)(wb + 3 * 512); acc = MFMA32(wf, cb3, acc);
                wf = *(const bf16x8*)(wb + 4 * 512); acc = MFMA32(wf, cb4, acc);
                wf = *(const bf16x8*)(wb + 5 * 512); acc = MFMA32(wf, cb5, acc);
                wf = *(const bf16x8*)(wb + 6 * 512); acc = MFMA32(wf, cb6, acc);
                wf = *(const bf16x8*)(wb + 7 * 512); acc = MFMA32(wf, cb7, acc);
            }
            __syncthreads();   // all cur reads done before this layer's cur overwrite
        }

        // ---- epilogue: bias+relu (fp32), estimator dot, cur -> Ab (bf16) ----
        // D[n][token]: token = lane&31, n = (reg&3) + 8*(reg>>2) + 4*hi (+32*nf)
        float p = 0.f;
        #pragma unroll
        for (int rg = 0; rg < 4; ++rg) {
            int nb = nf * 32 + rg * 8 + hi * 4;
            f4 bv = *(const f4*)(bl + d * D_ + nb);
            f4 ev = *(const f4*)(We + d * D_ + nb);
            float c0 = fmaxf(acc[rg * 4 + 0] + bv[0], 0.f);
            float c1 = fmaxf(acc[rg * 4 + 1] + bv[1], 0.f);
            float c2 = fmaxf(acc[rg * 4 + 2] + bv[2], 0.f);
            float c3 = fmaxf(acc[rg * 4 + 3] + bv[3], 0.f);
            p += c0 * ev[0] + c1 * ev[1] + c2 * ev[2] + c3 * ev[3];
            if (d < LAYERS - 1) {
                bf16x4 cc;
                cc[0] = (__bf16)c0; cc[1] = (__bf16)c1;
                cc[2] = (__bf16)c2; cc[3] = (__bf16)c3;
                *(bf16x4*)(Ab + swz(tok0, nb * 2)) = cc;
            }
        }
        p += __shfl_xor(p, 32, 64);          // combine hi halves (same token)
        if (lane < 32) PR[nf][tok0] = p;
        __syncthreads();   // cur + PR visible; orders PR reads before next layer's writes

        if (t < BM)
            outc += CSM[t][d] * (PR[0][t] + PR[1][t] + PR[2][t] + PR[3][t] + be[d]);
    }

    if (t < BM) out[m0 + t] = outc;
}

extern "C" void kernel_launch(void* const* d_in, const int* in_sizes, int n_in,
                              void* d_out, int out_size, void* d_ws, size_t ws_size,
                              hipStream_t stream) {
    const float* x  = (const float*)d_in[0];
    const float* Wr = (const float*)d_in[1];
    const float* Wl = (const float*)d_in[2];
    const float* bl = (const float*)d_in[3];
    const float* We = (const float*)d_in[4];
    const float* be = (const float*)d_in[5];
    float* out = (float*)d_out;
    __bf16* wt2 = (__bf16*)d_ws;                // 256 KB scratch for W^T frags
    const int B = in_sizes[0] / D_;             // 131072

    prep<<<dim3(512), dim3(256), 0, stream>>>(Wl, wt2);
    moe_fwd<<<dim3(B / BM), dim3(NT), 0, stream>>>(x, Wr, wt2, bl, We, be, out);
}

// Round 12
// 54.320 us; speedup vs baseline: 2.8646x; 2.8646x over previous
//
#include <hip/hip_runtime.h>
#include <cstddef>

typedef float f4 __attribute__((ext_vector_type(4)));
typedef __bf16 bf16x8 __attribute__((ext_vector_type(8)));
typedef __bf16 bf16x4 __attribute__((ext_vector_type(4)));
typedef float f32x16 __attribute__((ext_vector_type(16)));

constexpr int D_ = 128;     // d_model
constexpr int LAYERS = 4;
constexpr int BM = 128;     // tokens per block
constexpr int NT = 512;     // 8 waves: 4 nf (32-n frags) x 2 tw (64-token halves)
constexpr int ROWB = 512;   // A-tile row stride bytes (256 bf16)

// XOR swizzle (T2/G4): spreads 16B slots across banks for stride-512B rows.
__device__ __forceinline__ int swz(int row, int woff) {
    return row * ROWB + (woff ^ ((row & 15) << 4));
}

// prep: W^T in MFMA A-fragment order.
// wt2[((d*4 + nf)*16 + kc)*512 + lane*8 + j] = W^T[d][n = nf*32 + (lane&31)]
//                                                  [k = kc*16 + (lane>>5)*8 + j]
// Layer 0 folds concat([x,x]): top+bot summed into k in [128,256), zeros below.
__global__ void prep(const float* __restrict__ Wl, __bf16* __restrict__ wt2) {
    int idx = blockIdx.x * 256 + threadIdx.x;        // 4*4*16*512 = 131072
    int j = idx & 7, lane = (idx >> 3) & 63, kc = (idx >> 9) & 15,
        nf = (idx >> 13) & 3, d = idx >> 15;
    int n  = nf * 32 + (lane & 31);
    int ks = kc * 16 + (lane >> 5) * 8 + j;
    float v;
    if (d == 0)
        v = (ks < 128) ? 0.f
                       : (Wl[(size_t)(ks - 128) * D_ + n] + Wl[(size_t)ks * D_ + n]);
    else
        v = Wl[(size_t)d * 2 * D_ * D_ + (size_t)ks * D_ + j == j ? (size_t)ks * D_ + n : 0];
    // (the ternary above is a no-op guard kept simple: recompute plainly)
    if (d != 0)
        v = Wl[(size_t)d * 2 * D_ * D_ + (size_t)ks * D_ + n];
    wt2[idx] = (__bf16)v;
}

#define MFMA32(A, B, C) __builtin_amdgcn_mfma_f32_32x32x16_bf16((A), (B), (C), 0, 0, 0)

__global__ __launch_bounds__(NT, 4)   // 4 waves/SIMD, VGPR cap 128 (target ~90)
void moe_fwd(const float* __restrict__ x, const float* __restrict__ Wr,
             const __bf16* __restrict__ wt2, const float* __restrict__ bl,
             const float* __restrict__ We, const float* __restrict__ be,
             float* __restrict__ out)
{
    __shared__ char Ab[BM * ROWB];     // 64 KB: [token][256 k] bf16 swizzled (k<128 cur, k>=128 x)
    __shared__ float PR[4][BM];        // per-nf estimator partials
    __shared__ float CSM[BM][4];       // per-token 0/1 gate coefs

    const int t    = threadIdx.x;
    const int m0   = blockIdx.x * BM;
    const int lane = t & 63, w = t >> 6;
    const int nf   = w >> 1;            // 0..3: n in [nf*32, nf*32+32)
    const int tw   = w & 1;             // 0..1: token half
    const int lo5  = lane & 31, hi = lane >> 5;
    const int hi16 = hi * 16;
    const int tok0 = tw * 64 + lo5, tok1 = tok0 + 32;
    const int grp  = t >> 4, il = t & 15;   // 16 lanes per token row

    // ---- per-lane Wr rows (k = il*8 .. il*8+7), held in regs for gate dots ----
    f4 wrv[8];
    #pragma unroll
    for (int j = 0; j < 8; ++j)
        wrv[j] = *(const f4*)(Wr + (il * 8 + j) * 4);

    // ---- fused: stage x -> Ab (bf16, swizzled) + f64 gates from same registers ----
    #pragma unroll
    for (int i = 0; i < 4; ++i) {
        const int row = i * 32 + grp;
        const f4* gx = (const f4*)(x + (size_t)(m0 + row) * D_ + il * 8);
        f4 lo = gx[0], hp = gx[1];
        bf16x8 v;
        v[0] = (__bf16)lo[0]; v[1] = (__bf16)lo[1]; v[2] = (__bf16)lo[2]; v[3] = (__bf16)lo[3];
        v[4] = (__bf16)hp[0]; v[5] = (__bf16)hp[1]; v[6] = (__bf16)hp[2]; v[7] = (__bf16)hp[3];
        *(bf16x8*)(Ab + swz(row, 256 + il * 16)) = v;

        double a0 = 0, a1 = 0, a2 = 0, a3 = 0;
        #pragma unroll
        for (int j = 0; j < 4; ++j) {
            double xv = (double)lo[j];
            a0 += xv * (double)wrv[j][0]; a1 += xv * (double)wrv[j][1];
            a2 += xv * (double)wrv[j][2]; a3 += xv * (double)wrv[j][3];
        }
        #pragma unroll
        for (int j = 0; j < 4; ++j) {
            double xv = (double)hp[j];
            a0 += xv * (double)wrv[4 + j][0]; a1 += xv * (double)wrv[4 + j][1];
            a2 += xv * (double)wrv[4 + j][2]; a3 += xv * (double)wrv[4 + j][3];
        }
        #pragma unroll
        for (int s = 1; s < 16; s <<= 1) {   // 16-lane f64 tree reduce
            a0 += __shfl_xor(a0, s, 16);
            a1 += __shfl_xor(a1, s, 16);
            a2 += __shfl_xor(a2, s, 16);
            a3 += __shfl_xor(a3, s, 16);
        }
        if (il == 0) {
            f4 c;
            c[0] = a0 > 0.0 ? 1.f : 0.f; c[1] = a1 > 0.0 ? 1.f : 0.f;
            c[2] = a2 > 0.0 ? 1.f : 0.f; c[3] = a3 > 0.0 ? 1.f : 0.f;
            *(f4*)(&CSM[row][0]) = c;
        }
    }

    float outc = 0.f;
    __syncthreads();

    #pragma unroll
    for (int d = 0; d < LAYERS; ++d) {
        const int kstart = (d == 0) ? 8 : 0;   // layer 0: K=128 (x half only)

        f32x16 acc[2];
        #pragma unroll
        for (int tf = 0; tf < 2; ++tf)
            #pragma unroll
            for (int j = 0; j < 16; ++j) acc[tf][j] = 0.f;

        const __bf16* wb = wt2 + ((size_t)(d * 4 + nf) * 16) * 512 + lane * 8;

        // ---- software-pipelined k-loop: 4-deep rolling W window ----
        // wq[slot] holds the frag for ks; the slot is refilled for ks+4 right
        // after its value is captured, 4 MFMA-pairs before the refill's use.
        bf16x8 wq[4];
        #pragma unroll
        for (int i = 0; i < 4; ++i)
            wq[i] = *(const bf16x8*)(wb + (size_t)(kstart + i) * 512);

        #pragma unroll
        for (int ks = 0; ks < 16; ++ks) {
            if (ks < kstart) continue;           // compile-time (d unrolled)
            const int slot = ks & 3;             // compile-time after unroll
            bf16x8 wcur = wq[slot];
            if (ks + 4 < 16)
                wq[slot] = *(const bf16x8*)(wb + (size_t)(ks + 4) * 512);
            bf16x8 b0 = *(const bf16x8*)(Ab + swz(tok0, ks * 32 + hi16));
            bf16x8 b1 = *(const bf16x8*)(Ab + swz(tok1, ks * 32 + hi16));
            acc[0] = MFMA32(wcur, b0, acc[0]);
            acc[1] = MFMA32(wcur, b1, acc[1]);
        }
        __syncthreads();   // all Ab reads of this layer done before cur overwrite

        // ---- epilogue: bias+relu (fp32), estimator dot, cur -> Ab (bf16) ----
        // D[n][token]: token = lane&31, n = (reg&3) + 8*(reg>>2) + 4*hi (+32*nf)
        float p0 = 0.f, p1 = 0.f;
        #pragma unroll
        for (int rg = 0; rg < 4; ++rg) {
            int nb = nf * 32 + rg * 8 + hi * 4;
            f4 bv = *(const f4*)(bl + d * D_ + nb);
            f4 ev = *(const f4*)(We + d * D_ + nb);
            #pragma unroll
            for (int tf = 0; tf < 2; ++tf) {
                float c0 = fmaxf(acc[tf][rg * 4 + 0] + bv[0], 0.f);
                float c1 = fmaxf(acc[tf][rg * 4 + 1] + bv[1], 0.f);
                float c2 = fmaxf(acc[tf][rg * 4 + 2] + bv[2], 0.f);
                float c3 = fmaxf(acc[tf][rg * 4 + 3] + bv[3], 0.f);
                float pp = c0 * ev[0] + c1 * ev[1] + c2 * ev[2] + c3 * ev[3];
                if (tf == 0) p0 += pp; else p1 += pp;
                if (d < LAYERS - 1) {
                    bf16x4 cc;
                    cc[0] = (__bf16)c0; cc[1] = (__bf16)c1;
                    cc[2] = (__bf16)c2; cc[3] = (__bf16)c3;
                    int token = tw * 64 + tf * 32 + lo5;
                    *(bf16x4*)(Ab + swz(token, nb * 2)) = cc;
                }
            }
        }
        p0 += __shfl_xor(p0, 32, 64);
        p1 += __shfl_xor(p1, 32, 64);
        if (lane < 32) {
            PR[nf][tw * 64 + lo5]      = p0;
            PR[nf][tw * 64 + 32 + lo5] = p1;
        }
        __syncthreads();   // cur + PR (and, for d=0, CSM) visible

        if (t < BM)
            outc += CSM[t][d] * (PR[0][t] + PR[1][t] + PR[2][t] + PR[3][t] + be[d]);
    }

    if (t < BM) out[m0 + t] = outc;
}

extern "C" void kernel_launch(void* const* d_in, const int* in_sizes, int n_in,
                              void* d_out, int out_size, void* d_ws, size_t ws_size,
                              hipStream_t stream) {
    const float* x  = (const float*)d_in[0];
    const float* Wr = (const float*)d_in[1];
    const float* Wl = (const float*)d_in[2];
    const float* bl = (const float*)d_in[3];
    const float* We = (const float*)d_in[4];
    const float* be = (const float*)d_in[5];
    float* out = (float*)d_out;
    __bf16* wt2 = (__bf16*)d_ws;                // 256 KB scratch for W^T frags
    const int B = in_sizes[0] / D_;             // 131072

    prep<<<dim3(512), dim3(256), 0, stream>>>(Wl, wt2);
    moe_fwd<<<dim3(B / BM), dim3(NT), 0, stream>>>(x, Wr, wt2, bl, We, be, out);
}